// Round 3
// baseline (159.450 us; speedup 1.0000x reference)
//
#include <hip/hip_runtime.h>
#include <math.h>

#define EPS 1e-12f
#define NN 8
#define TT 2048
#define DD 512
#define KK 64
#define TC 128   // t-rows per fused block
#define TP 136   // padded t-stride (shorts) for LDS tiles

typedef short short8 __attribute__((ext_vector_type(8)));
typedef float floatx4 __attribute__((ext_vector_type(4)));

__device__ __forceinline__ unsigned short f2bf(float f) {
    unsigned int u = __float_as_uint(f);
    u += 0x7FFFu + ((u >> 16) & 1u);
    return (unsigned short)(u >> 16);
}
__device__ __forceinline__ unsigned int pack2(float a, float b) {
    return (unsigned int)f2bf(a) | ((unsigned int)f2bf(b) << 16);
}

// ---------------------------------------------------------------------------
// ws layout (float units):
//   Wb    bf16 [K][D]            @ 0        (16384 floats of space)
//   part  f32  [N*16tc][K][D/..] @ 16384    (4194304)  [(n*16+tc)*64+k]*512+d
//   v     f32  [N*K][D]          @ 4210688  (262144)
//   asum  f32  [N*K]             @ 4472832
//   norms f32  [N*K]             @ 4473344
//   scale f32  [N*K]             @ 4473856
// total 4474368 floats = 17.9 MB
// ---------------------------------------------------------------------------

__global__ __launch_bounds__(256) void k0_prep(const float* __restrict__ W,
                                               unsigned short* __restrict__ Wb,
                                               float* __restrict__ asum) {
    int i = blockIdx.x * 256 + threadIdx.x;  // < 32768
    Wb[i] = f2bf(W[i]);
    if (i < NN * KK) asum[i] = 0.0f;
}

// Fused normalize + assign(softmax) + vlad-contract.
// Block = (n, tc of 128 t, dh of 256 d), 512 threads (8 waves), grid 256.
// Phase 0: each wave owns a 16-row strip; lane(l,q) loads x[row=l][d=s*32+q*8..+7]
//          raw-bf16 into A-frags (regs) + stages its dh-half into sX[d][t] LDS.
//          ssq reduced over q -> s_t (row scale), kept OUT of the data.
// Phase 1: logits = s_t*(x*W)+b via MFMA (W from global, L1/L2-hot), softmax
//          over K=64 in registers, asum atomic (dh==0 only), a*s_t -> sA[k][t].
// Phase 2: part[k][d] = sum_t sA[k][t]*sX[d][t] via MFMA, store slice.
__global__ __launch_bounds__(512) void k123(const float* __restrict__ x,
                                            const unsigned short* __restrict__ Wb,
                                            const float* __restrict__ bias,
                                            float* __restrict__ part,
                                            float* __restrict__ asum) {
    __shared__ unsigned short sX[256 * TP];  // [d_local][t] raw x bf16 (dh half)
    __shared__ unsigned short sA[64 * TP];   // [k][t]  a*s_t bf16

    const int tid = threadIdx.x;
    const int w = tid >> 6, lane = tid & 63;
    const int l = lane & 15, q = lane >> 4;
    const int bid = blockIdx.x;
    const int dh = bid & 1, tc = (bid >> 1) & 15, n = bid >> 5;
    const int t0 = tc * TC;

    // ---- phase 0 ----
    const int row = n * TT + t0 + w * 16 + l;
    const float4* xr = (const float4*)(x + (size_t)row * DD) + q * 2;
    short8 fragA[16];
    float ssq = 0.0f;
#pragma unroll
    for (int s = 0; s < 16; ++s) {
        float4 u0 = xr[s * 8];
        float4 u1 = xr[s * 8 + 1];
        ssq += u0.x*u0.x + u0.y*u0.y + u0.z*u0.z + u0.w*u0.w
             + u1.x*u1.x + u1.y*u1.y + u1.z*u1.z + u1.w*u1.w;
        uint4 pk;
        pk.x = pack2(u0.x, u0.y); pk.y = pack2(u0.z, u0.w);
        pk.z = pack2(u1.x, u1.y); pk.w = pack2(u1.z, u1.w);
        union { uint4 u; short8 s8; } cvt; cvt.u = pk;
        fragA[s] = cvt.s8;
        if ((s >> 3) == dh) {  // stage this d-range into sX[d][t]
            int dloc = (s & 7) * 32 + q * 8;
            unsigned short* p = sX + (size_t)dloc * TP + w * 16 + l;
            p[0*TP] = (unsigned short)(pk.x);  p[1*TP] = (unsigned short)(pk.x >> 16);
            p[2*TP] = (unsigned short)(pk.y);  p[3*TP] = (unsigned short)(pk.y >> 16);
            p[4*TP] = (unsigned short)(pk.z);  p[5*TP] = (unsigned short)(pk.z >> 16);
            p[6*TP] = (unsigned short)(pk.w);  p[7*TP] = (unsigned short)(pk.w >> 16);
        }
    }
    ssq += __shfl_xor(ssq, 16, 64);
    ssq += __shfl_xor(ssq, 32, 64);
    float st = 1.0f / fmaxf(sqrtf(ssq), EPS);  // scale for row (w*16 + l)

    // ---- phase 1 ----
    const unsigned short* wp0 = Wb + (size_t)(0 * 16 + l) * DD + q * 8;
    const unsigned short* wp1 = Wb + (size_t)(1 * 16 + l) * DD + q * 8;
    const unsigned short* wp2 = Wb + (size_t)(2 * 16 + l) * DD + q * 8;
    const unsigned short* wp3 = Wb + (size_t)(3 * 16 + l) * DD + q * 8;
    floatx4 acc0 = {0.f, 0.f, 0.f, 0.f}, acc1 = acc0, acc2 = acc0, acc3 = acc0;
#pragma unroll
    for (int s = 0; s < 16; ++s) {
        acc0 = __builtin_amdgcn_mfma_f32_16x16x32_bf16(fragA[s], *(const short8*)(wp0 + s * 32), acc0, 0, 0, 0);
        acc1 = __builtin_amdgcn_mfma_f32_16x16x32_bf16(fragA[s], *(const short8*)(wp1 + s * 32), acc1, 0, 0, 0);
        acc2 = __builtin_amdgcn_mfma_f32_16x16x32_bf16(fragA[s], *(const short8*)(wp2 + s * 32), acc2, 0, 0, 0);
        acc3 = __builtin_amdgcn_mfma_f32_16x16x32_bf16(fragA[s], *(const short8*)(wp3 + s * 32), acc3, 0, 0, 0);
    }
    // per-C-row scales: row r of this lane's C tile is t_local = w*16 + 4q + r,
    // whose s_t lives in lane (4q + r) (q'=0 copy)
    float sr[4];
#pragma unroll
    for (int r = 0; r < 4; ++r) sr[r] = __shfl(st, 4 * q + r, 64);

    float bj0 = bias[0 * 16 + l], bj1 = bias[1 * 16 + l];
    float bj2 = bias[2 * 16 + l], bj3 = bias[3 * 16 + l];
    float av[4][4];  // [h][r]
#pragma unroll
    for (int r = 0; r < 4; ++r) {
        float v0 = acc0[r] * sr[r] + bj0, v1 = acc1[r] * sr[r] + bj1;
        float v2 = acc2[r] * sr[r] + bj2, v3 = acc3[r] * sr[r] + bj3;
        float m = fmaxf(fmaxf(v0, v1), fmaxf(v2, v3));
#pragma unroll
        for (int msk = 1; msk <= 8; msk <<= 1) m = fmaxf(m, __shfl_xor(m, msk, 64));
        float e0 = __expf(v0 - m), e1 = __expf(v1 - m), e2 = __expf(v2 - m), e3 = __expf(v3 - m);
        float ssum = e0 + e1 + e2 + e3;
#pragma unroll
        for (int msk = 1; msk <= 8; msk <<= 1) ssum += __shfl_xor(ssum, msk, 64);
        float inv = 1.0f / ssum;
        av[0][r] = e0 * inv; av[1][r] = e1 * inv; av[2][r] = e2 * inv; av[3][r] = e3 * inv;
    }

    if (dh == 0) {  // asum with UNSCALED a; avoid dh duplication
#pragma unroll
        for (int h = 0; h < 4; ++h) {
            float sh = av[h][0] + av[h][1] + av[h][2] + av[h][3];
            sh += __shfl_xor(sh, 16, 64);
            sh += __shfl_xor(sh, 32, 64);
            if (q == 0) atomicAdd(&asum[n * KK + h * 16 + l], sh);
        }
    }

    // a * s_t -> sA[k][t]
#pragma unroll
    for (int h = 0; h < 4; ++h) {
        unsigned short* p = sA + (size_t)(h * 16 + l) * TP + w * 16 + 4 * q;
        *(unsigned int*)(p)     = pack2(av[h][0] * sr[0], av[h][1] * sr[1]);
        *(unsigned int*)(p + 2) = pack2(av[h][2] * sr[2], av[h][3] * sr[3]);
    }
    __syncthreads();

    // ---- phase 2 ----
    const int mt = w & 3, dg = w >> 2;  // k-tile, d-group
    floatx4 pacc[8];
#pragma unroll
    for (int nt = 0; nt < 8; ++nt) pacc[nt] = floatx4{0.f, 0.f, 0.f, 0.f};
    const unsigned short* ap = sA + (size_t)(mt * 16 + l) * TP + q * 8;
    const unsigned short* bp = sX + (size_t)(dg * 128 + l) * TP + q * 8;
#pragma unroll
    for (int ks = 0; ks < 4; ++ks) {
        short8 af = *(const short8*)(ap + ks * 32);
#pragma unroll
        for (int nt = 0; nt < 8; ++nt) {
            short8 bf = *(const short8*)(bp + (size_t)nt * 16 * TP + ks * 32);
            pacc[nt] = __builtin_amdgcn_mfma_f32_16x16x32_bf16(af, bf, pacc[nt], 0, 0, 0);
        }
    }
    // store slice: row k = mt*16 + 4q + r, col d = dh*256 + dg*128 + nt*16 + l
    float* po = part + ((size_t)((n * 16 + tc) * 64) + mt * 16 + 4 * q) * DD
              + dh * 256 + dg * 128 + l;
#pragma unroll
    for (int nt = 0; nt < 8; ++nt)
#pragma unroll
        for (int r = 0; r < 4; ++r)
            po[(size_t)r * DD + nt * 16] = pacc[nt][r];
}

// K4a: v[nk][d] = sum_tc part - asum*c ; norms[nk] = ||v||^2
__global__ __launch_bounds__(64) void k4a_finish(const float* __restrict__ part,
                                                 const float* __restrict__ asum,
                                                 const float* __restrict__ cent,
                                                 float* __restrict__ v,
                                                 float* __restrict__ norms) {
    int nk = blockIdx.x;
    int n = nk >> 6, k = nk & 63;
    int lane = threadIdx.x;
    float as = asum[nk];
    const float* c = cent + (size_t)k * DD;
    float* vo = v + (size_t)nk * DD;
    float ssq = 0.0f;
#pragma unroll
    for (int j = 0; j < 8; ++j) {
        int d = lane + j * 64;
        float val = -as * c[d];
#pragma unroll
        for (int t = 0; t < 16; ++t)
            val += part[((size_t)((n * 16 + t) * 64 + k)) * DD + d];
        vo[d] = val;
        ssq += val * val;
    }
#pragma unroll
    for (int m = 32; m >= 1; m >>= 1) ssq += __shfl_xor(ssq, m, 64);
    if (lane == 0) norms[nk] = ssq;
}

// K4b: scale[n,k] = 1/(max(||v_nk||,eps) * max(g_n,eps))
__global__ __launch_bounds__(64) void k4b_scale(const float* __restrict__ norms,
                                                float* __restrict__ scale) {
    int n = blockIdx.x, k = threadIdx.x;
    float ssq = norms[n * KK + k];
    float nr = sqrtf(ssq);
    float dn = fmaxf(nr, EPS);
    float t = nr / dn;
    float g2 = t * t;
#pragma unroll
    for (int m = 32; m >= 1; m >>= 1) g2 += __shfl_xor(g2, m, 64);
    float g = sqrtf(g2);
    scale[n * KK + k] = 1.0f / (dn * fmaxf(g, EPS));
}

// K4c: out = v * scale[n,k]
__global__ __launch_bounds__(256) void k4c_out(const float* __restrict__ v,
                                               const float* __restrict__ scale,
                                               float* __restrict__ out) {
    int idx4 = blockIdx.x * 256 + threadIdx.x;
    int nk = idx4 >> 7;
    float s = scale[nk];
    float4 val = ((const float4*)v)[idx4];
    val.x *= s; val.y *= s; val.z *= s; val.w *= s;
    ((float4*)out)[idx4] = val;
}

extern "C" void kernel_launch(void* const* d_in, const int* in_sizes, int n_in,
                              void* d_out, int out_size, void* d_ws, size_t ws_size,
                              hipStream_t stream) {
    const float* x    = (const float*)d_in[0];
    const float* W    = (const float*)d_in[1];
    const float* b    = (const float*)d_in[2];
    const float* cent = (const float*)d_in[3];
    float* out = (float*)d_out;

    float* w = (float*)d_ws;
    unsigned short* Wb = (unsigned short*)(w + 0);
    float* part  = w + 16384;
    float* v     = w + 4210688;
    float* asum  = w + 4472832;
    float* norms = w + 4473344;
    float* scale = w + 4473856;

    hipLaunchKernelGGL(k0_prep,    dim3(128), dim3(256), 0, stream, W, Wb, asum);
    hipLaunchKernelGGL(k123,       dim3(256), dim3(512), 0, stream, x, Wb, b, part, asum);
    hipLaunchKernelGGL(k4a_finish, dim3(512), dim3(64),  0, stream, part, asum, cent, v, norms);
    hipLaunchKernelGGL(k4b_scale,  dim3(8),   dim3(64),  0, stream, norms, scale);
    hipLaunchKernelGGL(k4c_out,    dim3(256), dim3(256), 0, stream, v, scale, out);
}

// Round 4
// 108.546 us; speedup vs baseline: 1.4690x; 1.4690x over previous
//
#include <hip/hip_runtime.h>
#include <math.h>

#define EPS 1e-12f
#define NN 8
#define TT 2048
#define DD 512
#define KK 64

typedef short short8 __attribute__((ext_vector_type(8)));
typedef float floatx4 __attribute__((ext_vector_type(4)));

__device__ __forceinline__ unsigned short f2bf(float f) {
    unsigned int u = __float_as_uint(f);
    u += 0x7FFFu + ((u >> 16) & 1u);
    return (unsigned short)(u >> 16);
}
__device__ __forceinline__ unsigned int pack2(float a, float b) {
    return (unsigned int)f2bf(a) | ((unsigned int)f2bf(b) << 16);
}

// ---------------------------------------------------------------------------
// ws layout (float units):
//   Wb    bf16 [K][D]        @ 0         (16384)
//   xb    bf16 [N*T][D]      @ 16384     (4194304)   raw x, bf16
//   aTs   bf16 [N][K][T]     @ 4210688   (524288)    a * s_t
//   part  f32  [8tc][512nk][D] @ 4734976 (2097152)
//   v     f32  [512nk][D]    @ 6832128   (262144)
//   asum  f32  [512]         @ 7094272
//   norms f32  [512]         @ 7094784
// total 7095296 floats = 28.4 MB
// ---------------------------------------------------------------------------

// K0: W -> bf16; zero asum
__global__ __launch_bounds__(256) void k0_prep(const float* __restrict__ W,
                                               unsigned short* __restrict__ Wb,
                                               float* __restrict__ asum) {
    int i = blockIdx.x * 256 + threadIdx.x;  // < 32768
    Wb[i] = f2bf(W[i]);
    if (i < NN * KK) asum[i] = 0.0f;
}

// kA: fused L2-norm + assignment softmax. No LDS, no barriers.
// Wave = 16 t-rows. Writes xb (raw bf16 x) and aTs[k][t] = a*s_t, asum atomics.
__global__ __launch_bounds__(256) void kA(const float* __restrict__ x,
                                          const unsigned short* __restrict__ Wb,
                                          const float* __restrict__ bias,
                                          unsigned short* __restrict__ xb,
                                          unsigned short* __restrict__ aTs,
                                          float* __restrict__ asum) {
    const int tid = threadIdx.x;
    const int w = tid >> 6, lane = tid & 63;
    const int l = lane & 15, q = lane >> 4;
    const int row0 = blockIdx.x * 64 + w * 16;   // global t over N*T
    const int row = row0 + l;
    const int n = row0 >> 11;
    const int tl0 = row0 & (TT - 1);

    const float* xr = x + (size_t)row * DD;
    unsigned short* xo = xb + (size_t)row * DD;
    short8 fragA[16];
    float ssq = 0.0f;
#pragma unroll
    for (int s = 0; s < 16; ++s) {
        float4 u0 = *(const float4*)(xr + s * 32 + q * 8);
        float4 u1 = *(const float4*)(xr + s * 32 + q * 8 + 4);
        ssq += u0.x*u0.x + u0.y*u0.y + u0.z*u0.z + u0.w*u0.w
             + u1.x*u1.x + u1.y*u1.y + u1.z*u1.z + u1.w*u1.w;
        uint4 pk;
        pk.x = pack2(u0.x, u0.y); pk.y = pack2(u0.z, u0.w);
        pk.z = pack2(u1.x, u1.y); pk.w = pack2(u1.z, u1.w);
        union { uint4 u; short8 s8; } cvt; cvt.u = pk;
        fragA[s] = cvt.s8;
        *(uint4*)(xo + s * 32 + q * 8) = pk;
    }
    ssq += __shfl_xor(ssq, 16, 64);
    ssq += __shfl_xor(ssq, 32, 64);
    float st = 1.0f / fmaxf(sqrtf(ssq), EPS);

    floatx4 acc[4];
#pragma unroll
    for (int h = 0; h < 4; ++h) acc[h] = floatx4{0.f, 0.f, 0.f, 0.f};
#pragma unroll
    for (int s = 0; s < 16; ++s) {
#pragma unroll
        for (int h = 0; h < 4; ++h) {
            short8 wf = *(const short8*)(Wb + (size_t)(h * 16 + l) * DD + s * 32 + q * 8);
            acc[h] = __builtin_amdgcn_mfma_f32_16x16x32_bf16(fragA[s], wf, acc[h], 0, 0, 0);
        }
    }

    float sr[4];
#pragma unroll
    for (int r = 0; r < 4; ++r) sr[r] = __shfl(st, 4 * q + r, 64);
    float bj[4];
#pragma unroll
    for (int h = 0; h < 4; ++h) bj[h] = bias[h * 16 + l];

    float av[4][4];  // [h][r]
#pragma unroll
    for (int r = 0; r < 4; ++r) {
        float v0 = acc[0][r] * sr[r] + bj[0], v1 = acc[1][r] * sr[r] + bj[1];
        float v2 = acc[2][r] * sr[r] + bj[2], v3 = acc[3][r] * sr[r] + bj[3];
        float m = fmaxf(fmaxf(v0, v1), fmaxf(v2, v3));
#pragma unroll
        for (int msk = 1; msk <= 8; msk <<= 1) m = fmaxf(m, __shfl_xor(m, msk, 64));
        float e0 = __expf(v0 - m), e1 = __expf(v1 - m), e2 = __expf(v2 - m), e3 = __expf(v3 - m);
        float ssum = e0 + e1 + e2 + e3;
#pragma unroll
        for (int msk = 1; msk <= 8; msk <<= 1) ssum += __shfl_xor(ssum, msk, 64);
        float inv = 1.0f / ssum;
        av[0][r] = e0 * inv; av[1][r] = e1 * inv; av[2][r] = e2 * inv; av[3][r] = e3 * inv;
    }

    // aTs[n][k][t] = a * s_t (t = tl0 + 4q + r)
#pragma unroll
    for (int h = 0; h < 4; ++h) {
        uint2 p;
        p.x = pack2(av[h][0] * sr[0], av[h][1] * sr[1]);
        p.y = pack2(av[h][2] * sr[2], av[h][3] * sr[3]);
        *(uint2*)(aTs + ((size_t)(n * KK + h * 16 + l)) * TT + tl0 + 4 * q) = p;
    }
    // asum (unscaled a)
#pragma unroll
    for (int h = 0; h < 4; ++h) {
        float sh = av[h][0] + av[h][1] + av[h][2] + av[h][3];
        sh += __shfl_xor(sh, 16, 64);
        sh += __shfl_xor(sh, 32, 64);
        if (q == 0) atomicAdd(&asum[n * KK + h * 16 + l], sh);
    }
}

// kB: part[tc][n*64+k][d] = sum_{t in 256-chunk} aTs[k][t] * xb[t][d]
// Block = (n, dt of 64 d, tc of 256 t): 512 blocks, 4 waves (wave = k-tile).
// x transposed to LDS [d][64t] with XOR granule swizzle; double-buffered.
__global__ __launch_bounds__(256) void kB(const unsigned short* __restrict__ xb,
                                          const unsigned short* __restrict__ aTs,
                                          float* __restrict__ part) {
    __shared__ unsigned char smem[17408];  // 2x4096 ushort staging | 64x68 float transpose
    unsigned short* sX0 = (unsigned short*)smem;
    unsigned short* sX1 = sX0 + 4096;
    float* sT = (float*)smem;

    const int tid = threadIdx.x;
    const int wv = tid >> 6, lane = tid & 63;
    const int l = lane & 15, q = lane >> 4;
    const int bid = blockIdx.x;
    const int tc = bid & 7, dt = (bid >> 3) & 7, n = bid >> 6;

    // staging role: ts = t within 64-slice (lane id), dq = d-quarter (wave id)
    const int ts = tid & 63, dq = tid >> 6;
    const unsigned short* xbase = xb + ((size_t)(n * TT + tc * 256)) * DD + dt * 64 + dq * 16;
    const int g = ts >> 3, t7 = ts & 7;

#define STAGE(S, BUF)                                                          \
    {                                                                          \
        const unsigned short* p_ = xbase + (size_t)((S) * 64 + ts) * DD;       \
        unsigned short vals[16];                                               \
        *(uint4*)(vals) = *(const uint4*)(p_);                                 \
        *(uint4*)(vals + 8) = *(const uint4*)(p_ + 8);                         \
        _Pragma("unroll")                                                      \
        for (int e = 0; e < 16; ++e) {                                         \
            int d_ = dq * 16 + e;                                              \
            (BUF)[d_ * 64 + ((g ^ (d_ & 7)) << 3) + t7] = vals[e];             \
        }                                                                      \
    }

    floatx4 acc[4];
#pragma unroll
    for (int nt = 0; nt < 4; ++nt) acc[nt] = floatx4{0.f, 0.f, 0.f, 0.f};
    const unsigned short* abase = aTs + ((size_t)(n * KK + wv * 16 + l)) * TT + tc * 256;

    STAGE(0, sX0);
    __syncthreads();
#pragma unroll
    for (int s = 0; s < 4; ++s) {
        unsigned short* cur = (s & 1) ? sX1 : sX0;
        unsigned short* nxt = (s & 1) ? sX0 : sX1;
        if (s < 3) {
            if (s == 0) STAGE(1, nxt)
            else if (s == 1) STAGE(2, nxt)
            else STAGE(3, nxt)
        }
#pragma unroll
        for (int kb = 0; kb < 2; ++kb) {
            short8 af = *(const short8*)(abase + s * 64 + kb * 32 + q * 8);
            int gg = q + 4 * kb;
#pragma unroll
            for (int nt = 0; nt < 4; ++nt) {
                int d = nt * 16 + l;
                short8 bf = *(const short8*)(cur + d * 64 + ((gg ^ (d & 7)) << 3));
                acc[nt] = __builtin_amdgcn_mfma_f32_16x16x32_bf16(af, bf, acc[nt], 0, 0, 0);
            }
        }
        __syncthreads();
    }
#undef STAGE

    // transpose C through LDS -> coalesced 256B-row stores
#pragma unroll
    for (int nt = 0; nt < 4; ++nt)
#pragma unroll
        for (int r = 0; r < 4; ++r)
            sT[(wv * 16 + 4 * q + r) * 68 + nt * 16 + l] = acc[nt][r];
    __syncthreads();

    float* pbase = part + ((size_t)(tc * 512 + n * KK)) * DD + dt * 64;
    const int fq = tid & 15, kr = tid >> 4;
#pragma unroll
    for (int i = 0; i < 4; ++i) {
        int k = i * 16 + kr;
        float4 val = *(float4*)(sT + k * 68 + fq * 4);
        *(float4*)(pbase + (size_t)k * DD + fq * 4) = val;
    }
}

// kC: v[nk][d] = sum_tc part - asum*c ; norms[nk] = ||v||^2. Block per nk, 128 thr.
__global__ __launch_bounds__(128) void kC(const float* __restrict__ part,
                                          const float* __restrict__ asum,
                                          const float* __restrict__ cent,
                                          float* __restrict__ v,
                                          float* __restrict__ norms) {
    __shared__ float red[2];
    const int nk = blockIdx.x;
    const int k = nk & 63;
    const int tid = threadIdx.x;
    float as = asum[nk];
    float4 cc = ((const float4*)(cent + (size_t)k * DD))[tid];
    float4 a4 = make_float4(-as * cc.x, -as * cc.y, -as * cc.z, -as * cc.w);
#pragma unroll
    for (int tc = 0; tc < 8; ++tc) {
        float4 p = ((const float4*)(part + ((size_t)(tc * 512 + nk)) * DD))[tid];
        a4.x += p.x; a4.y += p.y; a4.z += p.z; a4.w += p.w;
    }
    ((float4*)(v + (size_t)nk * DD))[tid] = a4;
    float ssq = a4.x*a4.x + a4.y*a4.y + a4.z*a4.z + a4.w*a4.w;
#pragma unroll
    for (int m = 32; m >= 1; m >>= 1) ssq += __shfl_xor(ssq, m, 64);
    if ((tid & 63) == 0) red[tid >> 6] = ssq;
    __syncthreads();
    if (tid == 0) norms[nk] = red[0] + red[1];
}

// kD: out = v / (max(||v_nk||,eps) * max(g_n,eps)); g recomputed per block.
__global__ __launch_bounds__(256) void kD(const float* __restrict__ v,
                                          const float* __restrict__ norms,
                                          float* __restrict__ out) {
    const int n = blockIdx.x >> 3, kg = blockIdx.x & 7;
    const int tid = threadIdx.x;
    float g2 = 0.0f;
#pragma unroll
    for (int k = 0; k < 64; ++k) {
        float nr = sqrtf(norms[n * KK + k]);
        float t = nr / fmaxf(nr, EPS);
        g2 += t * t;
    }
    float g = sqrtf(g2);
    int k = kg * 8 + (tid >> 5);
    float nr = sqrtf(norms[n * KK + k]);
    float s = 1.0f / (fmaxf(nr, EPS) * fmaxf(g, EPS));
    const float4* vp = (const float4*)(v + ((size_t)(n * KK + k)) * DD) + (tid & 31) * 4;
    float4* op = (float4*)(out + ((size_t)(n * KK + k)) * DD) + (tid & 31) * 4;
#pragma unroll
    for (int i = 0; i < 4; ++i) {
        float4 t4 = vp[i];
        t4.x *= s; t4.y *= s; t4.z *= s; t4.w *= s;
        op[i] = t4;
    }
}

extern "C" void kernel_launch(void* const* d_in, const int* in_sizes, int n_in,
                              void* d_out, int out_size, void* d_ws, size_t ws_size,
                              hipStream_t stream) {
    const float* x    = (const float*)d_in[0];
    const float* W    = (const float*)d_in[1];
    const float* b    = (const float*)d_in[2];
    const float* cent = (const float*)d_in[3];
    float* out = (float*)d_out;

    float* w = (float*)d_ws;
    unsigned short* Wb  = (unsigned short*)(w + 0);
    unsigned short* xb  = (unsigned short*)(w + 16384);
    unsigned short* aTs = (unsigned short*)(w + 4210688);
    float* part  = w + 4734976;
    float* v     = w + 6832128;
    float* asum  = w + 7094272;
    float* norms = w + 7094784;

    hipLaunchKernelGGL(k0_prep, dim3(128), dim3(256), 0, stream, W, Wb, asum);
    hipLaunchKernelGGL(kA,      dim3(256), dim3(256), 0, stream, x, Wb, b, xb, aTs, asum);
    hipLaunchKernelGGL(kB,      dim3(512), dim3(256), 0, stream, xb, aTs, part);
    hipLaunchKernelGGL(kC,      dim3(512), dim3(128), 0, stream, part, asum, cent, v, norms);
    hipLaunchKernelGGL(kD,      dim3(64),  dim3(256), 0, stream, v, norms, out);
}

// Round 5
// 96.466 us; speedup vs baseline: 1.6529x; 1.1252x over previous
//
#include <hip/hip_runtime.h>
#include <math.h>

#define EPS 1e-12f
#define NN 8
#define TT 2048
#define DD 512
#define KK 64

typedef short short8 __attribute__((ext_vector_type(8)));
typedef float floatx4 __attribute__((ext_vector_type(4)));

__device__ __forceinline__ unsigned short f2bf(float f) {
    unsigned int u = __float_as_uint(f);
    u += 0x7FFFu + ((u >> 16) & 1u);
    return (unsigned short)(u >> 16);
}
__device__ __forceinline__ unsigned int pack2(float a, float b) {
    return (unsigned int)f2bf(a) | ((unsigned int)f2bf(b) << 16);
}

// ---------------------------------------------------------------------------
// ws layout (float units):
//   xb    bf16 [N*T][D]       @ 0        (4194304)   raw x, bf16
//   aTs   bf16 [N][K][T]      @ 4194304  (524288)    a * s_t
//   part  f32  [8tc][512nk][D]@ 4718592  (2097152)
//   asumP f32  [256blk][64k]  @ 6815744  (16384)     per-block unscaled a sums
// total 6832128 floats = 27.3 MB
// ---------------------------------------------------------------------------

// kA: fused W->bf16 (LDS, fragment-packed) + L2-norm + assignment softmax.
// Block = 64 t-rows (4 waves x 16 rows); grid 256 (1 block/CU).
// Writes xb (raw bf16 x), aTs[k][t] = a*s_t, asumP[block][k].
__global__ __launch_bounds__(256) void kA(const float* __restrict__ x,
                                          const float* __restrict__ W,
                                          const float* __restrict__ bias,
                                          unsigned short* __restrict__ xb,
                                          unsigned short* __restrict__ aTs,
                                          float* __restrict__ asumP) {
    // sW: fragment-packed Wb. Slot ((s*4+h)*64 + lane) holds
    // W[h*16 + (lane&15)][s*32 + (lane>>4)*8 .. +7] as 8 bf16 (16 B).
    // Frag reads are lane-contiguous ds_read_b128 -> conflict-free.
    __shared__ unsigned short sW[32768];  // 64 KB
    __shared__ float sRed[256];

    const int tid = threadIdx.x;

    // ---- x row load + normalize scale (issue HBM loads first) ----
    const int w = tid >> 6, lane = tid & 63;
    const int l = lane & 15, q = lane >> 4;
    const int row0 = blockIdx.x * 64 + w * 16;
    const int row = row0 + l;
    const int n = row0 >> 11;
    const int tl0 = row0 & (TT - 1);

    const float* xr = x + (size_t)row * DD;
    unsigned short* xo = xb + (size_t)row * DD;
    short8 fragA[16];
    float ssq = 0.0f;
#pragma unroll
    for (int s = 0; s < 16; ++s) {
        float4 u0 = *(const float4*)(xr + s * 32 + q * 8);
        float4 u1 = *(const float4*)(xr + s * 32 + q * 8 + 4);
        ssq += u0.x*u0.x + u0.y*u0.y + u0.z*u0.z + u0.w*u0.w
             + u1.x*u1.x + u1.y*u1.y + u1.z*u1.z + u1.w*u1.w;
        uint4 pk;
        pk.x = pack2(u0.x, u0.y); pk.y = pack2(u0.z, u0.w);
        pk.z = pack2(u1.x, u1.y); pk.w = pack2(u1.z, u1.w);
        union { uint4 u; short8 s8; } cvt; cvt.u = pk;
        fragA[s] = cvt.s8;
        *(uint4*)(xo + s * 32 + q * 8) = pk;
    }

    // ---- W -> LDS prologue (L2-hot; 128 elems/thread) ----
    {
        const int sp = tid >> 4, hp = (tid >> 2) & 3, qp = tid & 3;
        const float* wsrc = W + (size_t)(hp * 16) * DD + sp * 32 + qp * 8;
        unsigned short* wdst = sW + (size_t)tid * 128;  // 16 slots * 8 shorts
#pragma unroll
        for (int j = 0; j < 16; ++j) {
            float4 u0 = *(const float4*)(wsrc + (size_t)j * DD);
            float4 u1 = *(const float4*)(wsrc + (size_t)j * DD + 4);
            uint4 pk;
            pk.x = pack2(u0.x, u0.y); pk.y = pack2(u0.z, u0.w);
            pk.z = pack2(u1.x, u1.y); pk.w = pack2(u1.z, u1.w);
            *(uint4*)(wdst + j * 8) = pk;
        }
    }

    ssq += __shfl_xor(ssq, 16, 64);
    ssq += __shfl_xor(ssq, 32, 64);
    float st = 1.0f / fmaxf(sqrtf(ssq), EPS);

    __syncthreads();  // sW ready

    // ---- logits MFMA: B-frags from LDS ----
    floatx4 acc[4];
#pragma unroll
    for (int h = 0; h < 4; ++h) acc[h] = floatx4{0.f, 0.f, 0.f, 0.f};
#pragma unroll
    for (int s = 0; s < 16; ++s) {
#pragma unroll
        for (int h = 0; h < 4; ++h) {
            short8 wf = *(const short8*)(sW + ((size_t)((s * 4 + h) * 64) + lane) * 8);
            acc[h] = __builtin_amdgcn_mfma_f32_16x16x32_bf16(fragA[s], wf, acc[h], 0, 0, 0);
        }
    }

    float sr[4];
#pragma unroll
    for (int r = 0; r < 4; ++r) sr[r] = __shfl(st, 4 * q + r, 64);
    float bj[4];
#pragma unroll
    for (int h = 0; h < 4; ++h) bj[h] = bias[h * 16 + l];

    float av[4][4];  // [h][r]
#pragma unroll
    for (int r = 0; r < 4; ++r) {
        float v0 = acc[0][r] * sr[r] + bj[0], v1 = acc[1][r] * sr[r] + bj[1];
        float v2 = acc[2][r] * sr[r] + bj[2], v3 = acc[3][r] * sr[r] + bj[3];
        float m = fmaxf(fmaxf(v0, v1), fmaxf(v2, v3));
#pragma unroll
        for (int msk = 1; msk <= 8; msk <<= 1) m = fmaxf(m, __shfl_xor(m, msk, 64));
        float e0 = __expf(v0 - m), e1 = __expf(v1 - m), e2 = __expf(v2 - m), e3 = __expf(v3 - m);
        float ss = e0 + e1 + e2 + e3;
#pragma unroll
        for (int msk = 1; msk <= 8; msk <<= 1) ss += __shfl_xor(ss, msk, 64);
        float inv = 1.0f / ss;
        av[0][r] = e0 * inv; av[1][r] = e1 * inv; av[2][r] = e2 * inv; av[3][r] = e3 * inv;
    }

    // aTs[n][k][t] = a * s_t  (t = tl0 + 4q + r, k = h*16 + l)
#pragma unroll
    for (int h = 0; h < 4; ++h) {
        uint2 p;
        p.x = pack2(av[h][0] * sr[0], av[h][1] * sr[1]);
        p.y = pack2(av[h][2] * sr[2], av[h][3] * sr[3]);
        *(uint2*)(aTs + ((size_t)(n * KK + h * 16 + l)) * TT + tl0 + 4 * q) = p;
    }

    // per-block unscaled-a k-sums -> asumP[bid][k] (no atomics, no init kernel)
#pragma unroll
    for (int h = 0; h < 4; ++h) {
        float sh = av[h][0] + av[h][1] + av[h][2] + av[h][3];
        sh += __shfl_xor(sh, 16, 64);
        sh += __shfl_xor(sh, 32, 64);
        if (q == 0) sRed[w * 64 + h * 16 + l] = sh;
    }
    __syncthreads();
    if (tid < 64) {
        float s0 = sRed[tid] + sRed[64 + tid] + sRed[128 + tid] + sRed[192 + tid];
        asumP[(size_t)blockIdx.x * 64 + tid] = s0;
    }
}

// kB: part[tc][n*64+k][d] = sum_{t in 256-chunk} aTs[k][t] * xb[t][d]
// bid = dt*64 + (n*8 + tc): bid%8 == tc -> all 8 dt-blocks sharing an
// (n,tc) aTs/xb slice land on the same XCD (L2 reuse; aTs fetched once).
__global__ __launch_bounds__(256) void kB(const unsigned short* __restrict__ xb,
                                          const unsigned short* __restrict__ aTs,
                                          float* __restrict__ part) {
    __shared__ unsigned char smem[17408];  // 2x4096 ushort staging | 64x68 f32 transpose
    unsigned short* sX0 = (unsigned short*)smem;
    unsigned short* sX1 = sX0 + 4096;
    float* sT = (float*)smem;

    const int tid = threadIdx.x;
    const int wv = tid >> 6, lane = tid & 63;
    const int l = lane & 15, q = lane >> 4;
    const int bid = blockIdx.x;
    const int low = bid & 63;
    const int n = low >> 3, tc = low & 7, dt = bid >> 6;

    const int ts = tid & 63, dq = tid >> 6;
    const unsigned short* xbase = xb + ((size_t)(n * TT + tc * 256)) * DD + dt * 64 + dq * 16;
    const int g = ts >> 3, t7 = ts & 7;

#define STAGE(S, BUF)                                                          \
    {                                                                          \
        const unsigned short* p_ = xbase + (size_t)((S) * 64 + ts) * DD;       \
        unsigned short vals[16];                                               \
        *(uint4*)(vals) = *(const uint4*)(p_);                                 \
        *(uint4*)(vals + 8) = *(const uint4*)(p_ + 8);                         \
        _Pragma("unroll")                                                      \
        for (int e = 0; e < 16; ++e) {                                         \
            int d_ = dq * 16 + e;                                              \
            (BUF)[d_ * 64 + ((g ^ (d_ & 7)) << 3) + t7] = vals[e];             \
        }                                                                      \
    }

    floatx4 acc[4];
#pragma unroll
    for (int nt = 0; nt < 4; ++nt) acc[nt] = floatx4{0.f, 0.f, 0.f, 0.f};
    const unsigned short* abase = aTs + ((size_t)(n * KK + wv * 16 + l)) * TT + tc * 256;

    STAGE(0, sX0);
    __syncthreads();
#pragma unroll
    for (int s = 0; s < 4; ++s) {
        unsigned short* cur = (s & 1) ? sX1 : sX0;
        unsigned short* nxt = (s & 1) ? sX0 : sX1;
        if (s < 3) {
            if (s == 0) STAGE(1, nxt)
            else if (s == 1) STAGE(2, nxt)
            else STAGE(3, nxt)
        }
#pragma unroll
        for (int kb = 0; kb < 2; ++kb) {
            short8 af = *(const short8*)(abase + s * 64 + kb * 32 + q * 8);
            int gg = q + 4 * kb;
#pragma unroll
            for (int nt = 0; nt < 4; ++nt) {
                int d = nt * 16 + l;
                short8 bf = *(const short8*)(cur + d * 64 + ((gg ^ (d & 7)) << 3));
                acc[nt] = __builtin_amdgcn_mfma_f32_16x16x32_bf16(af, bf, acc[nt], 0, 0, 0);
            }
        }
        __syncthreads();
    }
#undef STAGE

    // transpose C through LDS -> coalesced 256 B row stores
#pragma unroll
    for (int nt = 0; nt < 4; ++nt)
#pragma unroll
        for (int r = 0; r < 4; ++r)
            sT[(wv * 16 + 4 * q + r) * 68 + nt * 16 + l] = acc[nt][r];
    __syncthreads();

    float* pbase = part + ((size_t)(tc * 512 + n * KK)) * DD + dt * 64;
    const int fq = tid & 15, kr = tid >> 4;
#pragma unroll
    for (int i = 0; i < 4; ++i) {
        int k = i * 16 + kr;
        float4 val = *(float4*)(sT + k * 68 + fq * 4);
        *(float4*)(pbase + (size_t)k * DD + fq * 4) = val;
    }
}

// kC: asum = sum(asumP); val = sum_tc part - asum*c; intra-norm + global-norm
// fold -> out. Global norm over 64 intra-normalized clusters is exactly
// sqrt(64)=8 (each cluster contributes ||v/max(||v||,eps)||^2 = 1.0; the
// reference deviates by <1e-6 rel, ~1e-8 on outputs).
__global__ __launch_bounds__(128) void kC(const float* __restrict__ part,
                                          const float* __restrict__ asumP,
                                          const float* __restrict__ cent,
                                          float* __restrict__ out) {
    __shared__ float red[2];
    __shared__ float sAsum;
    const int nk = blockIdx.x;
    const int n = nk >> 6, k = nk & 63;
    const int tid = threadIdx.x;

    if (tid < 32) {
        float p = asumP[(size_t)(n * 32 + tid) * 64 + k];
#pragma unroll
        for (int m = 16; m >= 1; m >>= 1) p += __shfl_xor(p, m, 64);
        if (tid == 0) sAsum = p;
    }
    __syncthreads();
    float as = sAsum;

    float4 cc = ((const float4*)(cent + (size_t)k * DD))[tid];
    float4 a4 = make_float4(-as * cc.x, -as * cc.y, -as * cc.z, -as * cc.w);
#pragma unroll
    for (int tc = 0; tc < 8; ++tc) {
        float4 p = ((const float4*)(part + ((size_t)(tc * 512 + nk)) * DD))[tid];
        a4.x += p.x; a4.y += p.y; a4.z += p.z; a4.w += p.w;
    }
    float ssq = a4.x*a4.x + a4.y*a4.y + a4.z*a4.z + a4.w*a4.w;
#pragma unroll
    for (int m = 32; m >= 1; m >>= 1) ssq += __shfl_xor(ssq, m, 64);
    if ((tid & 63) == 0) red[tid >> 6] = ssq;
    __syncthreads();
    float nr = sqrtf(red[0] + red[1]);
    float sc = 1.0f / (fmaxf(nr, EPS) * 8.0f);
    a4.x *= sc; a4.y *= sc; a4.z *= sc; a4.w *= sc;
    ((float4*)(out + (size_t)nk * DD))[tid] = a4;
}

extern "C" void kernel_launch(void* const* d_in, const int* in_sizes, int n_in,
                              void* d_out, int out_size, void* d_ws, size_t ws_size,
                              hipStream_t stream) {
    const float* x    = (const float*)d_in[0];
    const float* W    = (const float*)d_in[1];
    const float* b    = (const float*)d_in[2];
    const float* cent = (const float*)d_in[3];
    float* out = (float*)d_out;

    float* w = (float*)d_ws;
    unsigned short* xb  = (unsigned short*)(w + 0);
    unsigned short* aTs = (unsigned short*)(w + 4194304);
    float* part  = w + 4718592;
    float* asumP = w + 6815744;

    hipLaunchKernelGGL(kA, dim3(256), dim3(256), 0, stream, x, W, b, xb, aTs, asumP);
    hipLaunchKernelGGL(kB, dim3(512), dim3(256), 0, stream, xb, aTs, part);
    hipLaunchKernelGGL(kC, dim3(512), dim3(128), 0, stream, part, asumP, cent, out);
}